// Round 4
// baseline (121.703 us; speedup 1.0000x reference)
//
#include <hip/hip_runtime.h>
#include <hip/hip_bf16.h>

#define NC 2048       // combined rows: [0,1024) = left, [1024,2048) = right
#define NPAIR 1048576

typedef __attribute__((ext_vector_type(8))) short bf16x8;
typedef __attribute__((ext_vector_type(4))) float f32x4;
typedef __attribute__((ext_vector_type(2))) float f32x2;
typedef __attribute__((ext_vector_type(4))) unsigned int u32x4;

__device__ inline short f2bf(float f) {
    __hip_bfloat16 h = __float2bfloat16(f);
    return __builtin_bit_cast(short, h);
}
__device__ inline unsigned cvt_pk(float a, float b) {   // lo=bf16(a), hi=bf16(b), RNE
    unsigned r;
    asm("v_cvt_pk_bf16_f32 %0, %1, %2" : "=v"(r) : "v"(a), "v"(b));
    return r;
}

// ---------------- K0: setup = xej mean + weight prep ----------------
__global__ void k_setup(const float* __restrict__ el, const float* __restrict__ er,
                        const float* __restrict__ Wc1, const float* __restrict__ Wn1, const float* __restrict__ We1,
                        const float* __restrict__ Wc2, const float* __restrict__ Wn2, const float* __restrict__ We2,
                        const float* __restrict__ Wc3, const float* __restrict__ Wn3, const float* __restrict__ We3,
                        const float* __restrict__ A1,  const float* __restrict__ A2,  const float* __restrict__ A3,
                        float* __restrict__ xej,
                        float* __restrict__ WT1, float* __restrict__ WT2, float* __restrict__ WT3,
                        float* __restrict__ A1t, short* __restrict__ Bpp) {
    int t = threadIdx.x;
    if (blockIdx.x < 64) {                 // xej: 2048 rows x 32, f32x4 per thread
        int c = blockIdx.x * 32 + (t >> 3);
        int p = t & 7;
        const float* e = ((c < 1024) ? el : er) + (c & 1023) * 1024 + p * 4;
        f32x4 s = {0.f, 0.f, 0.f, 0.f};
#pragma unroll
        for (int k = 0; k < 32; ++k) {
            f32x4 v = *(const f32x4*)(e + k * 32);
#pragma unroll
            for (int q = 0; q < 4; ++q) s[q] += v[q];
        }
#pragma unroll
        for (int q = 0; q < 4; ++q) s[q] *= (1.f / 32.f);
        *(f32x4*)&xej[c * 32 + p * 4] = s;
        return;
    }
    int i = (blockIdx.x - 64) * 256 + t;
    if (i < 20480) {                       // WT1: (160 x 128), K-major
        int d = i >> 7, o = i & 127;
        WT1[i] = (d < 64) ? Wc1[o * 64 + d] : (d < 128) ? Wn1[o * 64 + (d - 64)] : We1[o * 32 + (d - 128)];
    } else if (i < 57344) {                // WT2: (288 x 128)
        int j = i - 20480; int d = j >> 7, o = j & 127;
        WT2[j] = (d < 128) ? Wc2[o * 128 + d] : (d < 256) ? Wn2[o * 128 + (d - 128)] : We2[o * 32 + (d - 256)];
    } else if (i < 75776) {                // WT3: (288 x 64)
        int j = i - 57344; int d = j >> 6, o = j & 63;
        WT3[j] = (d < 128) ? Wc3[o * 128 + d] : (d < 256) ? Wn3[o * 128 + (d - 128)] : We3[o * 32 + (d - 256)];
    } else if (i < 83968) {                // A1t: (64 x 128), 0.5 folded in
        int j = i - 75776; int d = j >> 7, o = j & 127;
        A1t[j] = 0.5f * A1[o * 64 + d];
    } else if (i < 92160) {                // A2 frags: 16 x 64 lanes x 8, permuted h2 rows
        int j = i - 83968;
        int ktnt = j >> 9, l = (j >> 3) & 63, e = j & 7;
        int kt = ktnt >> 2, nt = ktnt & 3;
        int m = l & 15;
        int o = (nt >> 1) * 32 + (m >> 2) * 8 + (nt & 1) * 4 + (m & 3);   // permuted row
        int k = kt * 32 + (l >> 4) * 8 + e;
        Bpp[j] = f2bf(A2[o * 128 + k]);
    } else if (i < 94208) {                // A3 frags: (c,p=hi/lo) x 64 lanes x 8
        int j = i - 92160;
        int cp = j >> 9, l = (j >> 3) & 63, e = j & 7;
        int c = cp >> 1, p = cp & 1;
        int m = l & 15;
        int h2 = c * 32 + (l >> 4) * 8 + e;
        float v = (m < 2) ? A3[m * 64 + h2] : 0.f;
        short hi = f2bf(v);
        float vh = __bfloat162float(__builtin_bit_cast(__hip_bfloat16, hi));
        Bpp[8192 + j] = p ? f2bf(v - vh) : hi;
    }
}

// ---------------- K1: gather -> concat input, column-major CT (K x 2048) ----------------
template<int NIN>
__global__ void k_gather(const float* __restrict__ xl, const float* __restrict__ xr,
                         const int* __restrict__ ijl, const int* __restrict__ ijr,
                         const float* __restrict__ xej, float* __restrict__ CT) {
    int t = threadIdx.x;
    int d = t & (NIN - 1);
    int c = blockIdx.x * (256 / NIN) + t / NIN;   // c wave-uniform
    int n = c & 1023;
    bool left = (c < 1024);
    const float* xp = left ? xl : xr;
    const int*  ijp = left ? ijl : ijr;
    int nb = __builtin_amdgcn_readfirstlane(n);
    CT[d * NC + c] = xp[n * NIN + d];
    float s = 0.f;
#pragma unroll
    for (int k = 0; k < 32; ++k) {
        int nh = ijp[nb * 32 + k];                // s_load (uniform)
        s += xp[nh * NIN + d];                    // coalesced vector load
    }
    CT[(NIN + d) * NC + c] = s * (1.f / 32.f);
    if (d < 32) CT[(2 * NIN + d) * NC + c] = xej[c * 32 + d];
}

// ---------------- K2: full-K small GEMM, 2 outs/thread, wave-uniform weights ----------------
// out(n,o) = act( sum_d in[d][n] * WT[d][o] );  in column-major stride NC
template<int K, int NOUT, bool TRANS, bool RELU>
__global__ __launch_bounds__(64) void k_gemm(const float* __restrict__ in,
                                             const float* __restrict__ WT,
                                             float* __restrict__ out) {
    int n  = blockIdx.x * 64 + threadIdx.x;
    int o0 = blockIdx.y * 2;
    float a0 = 0.f, a1 = 0.f;
#pragma unroll 8
    for (int d = 0; d < K; ++d) {
        float xd = in[d * NC + n];
        const float* w = WT + d * NOUT + o0;      // wave-uniform -> s_load
        a0 = fmaf(w[0], xd, a0);
        a1 = fmaf(w[1], xd, a1);
    }
    if (RELU) { a0 = fmaxf(a0, 0.f); a1 = fmaxf(a1, 0.f); }
    if (TRANS) {
        out[o0 * NC + n] = a0;                    // column-major, 256B coalesced
        out[(o0 + 1) * NC + n] = a1;
    } else {
        *(f32x2*)&out[n * NOUT + o0] = f32x2{a0, a1};
    }
}

// ---------------- K3: dense over 1M pairs, double-MFMA, 2 i-rows/wave ----------------
__global__ __launch_bounds__(256, 2) void k_dense(const float* __restrict__ U,
                                                  const short* __restrict__ Bpp,
                                                  float* __restrict__ out) {
    __shared__ float ur[64 * 132];
    int t = threadIdx.x;
    int lane = t & 63;
    int w = t >> 6;
    int j0 = blockIdx.x * 64;
    int iA = blockIdx.y * 8 + w * 2;          // this wave's two pair-rows
    int iB = iA + 1;
    int col = lane & 15, g = lane >> 4;

    // stage Ur tile (64 rows x 128) into LDS, f32x4 coalesced
    for (int idx = t; idx < 2048; idx += 256) {
        int r = idx >> 5, k4 = (idx & 31) << 2;
        *(f32x4*)&ur[r * 132 + k4] = *(const f32x4*)&U[(1024 + j0 + r) * 128 + k4];
    }

    // A2 frags (A-operand, permuted rows) + A3 hi/lo frags: registers all kernel
    bf16x8 a2f[4][4];
#pragma unroll
    for (int kt = 0; kt < 4; ++kt)
#pragma unroll
        for (int nt = 0; nt < 4; ++nt)
            a2f[kt][nt] = *(const bf16x8*)&Bpp[((kt * 4 + nt) * 64 + lane) * 8];
    bf16x8 a3f[2][2];
#pragma unroll
    for (int c = 0; c < 2; ++c)
#pragma unroll
        for (int p = 0; p < 2; ++p)
            a3f[c][p] = *(const bf16x8*)&Bpp[8192 + ((c * 2 + p) * 64 + lane) * 8];

    // Ul slices (k = kt*32 + g*8 + e) for both rows, as f32x2 pairs
    f32x2 ulA[4][4], ulB[4][4];
#pragma unroll
    for (int kt = 0; kt < 4; ++kt) {
        const float* pA = U + iA * 128 + kt * 32 + g * 8;
        const float* pB = U + iB * 128 + kt * 32 + g * 8;
#pragma unroll
        for (int q = 0; q < 4; ++q) {
            ulA[kt][q] = *(const f32x2*)(pA + q * 2);
            ulB[kt][q] = *(const f32x2*)(pB + q * 2);
        }
    }

    __syncthreads();

    const f32x2 z2 = {0.f, 0.f};
    for (int jg = 0; jg < 4; ++jg) {
        const float* urow = ur + (jg * 16 + col) * 132 + g * 8;
        bf16x8 h1A[4], h1B[4];
#pragma unroll
        for (int kt = 0; kt < 4; ++kt) {
            u32x4 pwA, pwB;
#pragma unroll
            for (int q = 0; q < 4; ++q) {
                f32x2 u = *(const f32x2*)(urow + kt * 32 + q * 2);
                f32x2 sA = __builtin_elementwise_max(ulA[kt][q] + u, z2);   // v_pk_add/max
                f32x2 sB = __builtin_elementwise_max(ulB[kt][q] + u, z2);
                pwA[q] = cvt_pk(sA[0], sA[1]);
                pwB[q] = cvt_pk(sB[0], sB[1]);
            }
            h1A[kt] = __builtin_bit_cast(bf16x8, pwA);
            h1B[kt] = __builtin_bit_cast(bf16x8, pwB);
        }
        // h2t = A2 @ h1 for both rows (independent MFMA chains -> ILP)
        f32x4 acc1A[4] = {{0,0,0,0},{0,0,0,0},{0,0,0,0},{0,0,0,0}};
        f32x4 acc1B[4] = {{0,0,0,0},{0,0,0,0},{0,0,0,0},{0,0,0,0}};
#pragma unroll
        for (int nt = 0; nt < 4; ++nt)
#pragma unroll
            for (int kt = 0; kt < 4; ++kt) {
                acc1A[nt] = __builtin_amdgcn_mfma_f32_16x16x32_bf16(a2f[kt][nt], h1A[kt], acc1A[nt], 0, 0, 0);
                acc1B[nt] = __builtin_amdgcn_mfma_f32_16x16x32_bf16(a2f[kt][nt], h1B[kt], acc1B[nt], 0, 0, 0);
            }
        // out = (A3hi + A3lo) @ relu(h2), acc1 regs feed B-frag directly (row perm)
        f32x4 accOA = {0,0,0,0}, accOB = {0,0,0,0};
#pragma unroll
        for (int c = 0; c < 2; ++c) {
            u32x4 pwA, pwB;
#pragma unroll
            for (int h = 0; h < 2; ++h) {
                f32x4 rA = __builtin_elementwise_max(acc1A[2 * c + h], f32x4{0,0,0,0});
                f32x4 rB = __builtin_elementwise_max(acc1B[2 * c + h], f32x4{0,0,0,0});
                pwA[2 * h]     = cvt_pk(rA[0], rA[1]);
                pwA[2 * h + 1] = cvt_pk(rA[2], rA[3]);
                pwB[2 * h]     = cvt_pk(rB[0], rB[1]);
                pwB[2 * h + 1] = cvt_pk(rB[2], rB[3]);
            }
            bf16x8 hbA = __builtin_bit_cast(bf16x8, pwA);
            bf16x8 hbB = __builtin_bit_cast(bf16x8, pwB);
            accOA = __builtin_amdgcn_mfma_f32_16x16x32_bf16(a3f[c][0], hbA, accOA, 0, 0, 0);
            accOA = __builtin_amdgcn_mfma_f32_16x16x32_bf16(a3f[c][1], hbA, accOA, 0, 0, 0);
            accOB = __builtin_amdgcn_mfma_f32_16x16x32_bf16(a3f[c][0], hbB, accOB, 0, 0, 0);
            accOB = __builtin_amdgcn_mfma_f32_16x16x32_bf16(a3f[c][1], hbB, accOB, 0, 0, 0);
        }
        if (lane < 16) {
            int pA = iA * 1024 + j0 + jg * 16 + col;
            int pB = iB * 1024 + j0 + jg * 16 + col;
            out[pA]         = fmaxf(accOA[0], 0.f);
            out[NPAIR + pA] = fmaxf(accOA[1], 0.f);
            out[pB]         = fmaxf(accOB[0], 0.f);
            out[NPAIR + pB] = fmaxf(accOB[1], 0.f);
        }
    }
}

extern "C" void kernel_launch(void* const* d_in, const int* in_sizes, int n_in,
                              void* d_out, int out_size, void* d_ws, size_t ws_size,
                              hipStream_t stream) {
    const float* xnr = (const float*)d_in[0];
    const float* xer = (const float*)d_in[1];
    const int*   ijr = (const int*)  d_in[2];
    const float* xnl = (const float*)d_in[3];
    const float* xel = (const float*)d_in[4];
    const int*   ijl = (const int*)  d_in[5];
    const float* Wc1 = (const float*)d_in[6];
    const float* Wn1 = (const float*)d_in[7];
    const float* We1 = (const float*)d_in[8];
    const float* Wc2 = (const float*)d_in[9];
    const float* Wn2 = (const float*)d_in[10];
    const float* We2 = (const float*)d_in[11];
    const float* Wc3 = (const float*)d_in[12];
    const float* Wn3 = (const float*)d_in[13];
    const float* We3 = (const float*)d_in[14];
    const float* A1  = (const float*)d_in[15];
    const float* A2  = (const float*)d_in[16];
    const float* A3  = (const float*)d_in[17];
    float* out = (float*)d_out;

    float* ws  = (float*)d_ws;
    float* xej = ws;                   // 65536
    float* WT1 = xej + 65536;          // 20480
    float* WT2 = WT1 + 20480;          // 36864
    float* WT3 = WT2 + 36864;          // 18432
    float* A1t = WT3 + 18432;          // 8192
    short* Bpp = (short*)(A1t + 8192); // 10240 shorts = 5120 floats
    float* CT  = A1t + 8192 + 5120;    // 288*2048 = 589824
    float* XA  = CT + 589824;          // 2048*128 = 262144
    float* X3T = XA + 262144;          // 64*2048  = 131072 (column-major x3)
    float* U   = X3T + 131072;         // 2048*128 = 262144

    k_setup<<<432, 256, 0, stream>>>(xel, xer, Wc1, Wn1, We1, Wc2, Wn2, We2, Wc3, Wn3, We3,
                                     A1, A2, A3, xej, WT1, WT2, WT3, A1t, Bpp);
    // layer 1: 64 -> 128
    k_gather<64><<<512, 256, 0, stream>>>(xnl, xnr, ijl, ijr, xej, CT);
    k_gemm<160, 128, false, true><<<dim3(32, 64), 64, 0, stream>>>(CT, WT1, XA);
    // layer 2: 128 -> 128
    k_gather<128><<<1024, 256, 0, stream>>>(XA, XA + 1024 * 128, ijl, ijr, xej, CT);
    k_gemm<288, 128, false, true><<<dim3(32, 64), 64, 0, stream>>>(CT, WT2, XA);
    // layer 3: 128 -> 64, transpose-out -> X3T column-major
    k_gather<128><<<1024, 256, 0, stream>>>(XA, XA + 1024 * 128, ijl, ijr, xej, CT);
    k_gemm<288, 64, true, true><<<dim3(32, 32), 64, 0, stream>>>(CT, WT3, X3T);
    // U = 0.5 * A1 @ x3 (reads X3T column-major), row-major out
    k_gemm<64, 128, false, false><<<dim3(32, 64), 64, 0, stream>>>(X3T, A1t, U);
    // dense over all pairs
    k_dense<<<dim3(16, 128), 256, 0, stream>>>(U, Bpp, out);
}